// Round 11
// baseline (1282.008 us; speedup 1.0000x reference)
//
#include <hip/hip_runtime.h>

#define Bb 2
#define Nn 50000
#define Ee 512000
#define DE 128
#define HH 256
#define DO 128
#define TILES 782        // ceil(50000/64)
#define BINS_B 782       // bins per batch, 64 nodes each
#define NBINS (Bb * BINS_B)
#define CAPB 896         // bin capacity; Poisson(655)+9.4sigma
#define SPILL_MAX 65536

typedef __attribute__((ext_vector_type(8))) short short8;
typedef __attribute__((ext_vector_type(4))) float f32x4;

// Agent-scope atomic store: lay down the zeros that later atomicAdds RMW
// (round-3: plain-stored zeros + cross-kernel atomic RMW diverged in replay).
#define ATOMIC_ST(p, v) __hip_atomic_store((p), (v), __ATOMIC_RELAXED, __HIP_MEMORY_SCOPE_AGENT)

// f32 -> bf16 round-to-nearest-even (data has no NaN/Inf)
static __device__ __forceinline__ unsigned short f2bf(float f) {
  union { float f; unsigned int u; } x; x.f = f;
  return (unsigned short)((x.u + 0x7FFFu + ((x.u >> 16) & 1u)) >> 16);
}
// bf16 -> f32
static __device__ __forceinline__ float bf2f(unsigned short h) {
  union { unsigned int u; float f; } x; x.u = ((unsigned int)h) << 16;
  return x.f;
}

// Pre-convert W1/W2 into bf16 MFMA B-fragment order (one dwordx4 per frag).
__global__ void wconv_kernel(const float* __restrict__ W1, const float* __restrict__ W2,
                             unsigned short* __restrict__ w1f, unsigned short* __restrict__ w2f) {
  int t = blockIdx.x * 256 + threadIdx.x;
  if (t < 16 * 8 * 64) {
    int lane = t & 63, ks = (t >> 6) & 7, ct = t >> 9;
    int col = ct * 16 + (lane & 15);
    int k0 = ks * 32 + (lane >> 4) * 8;
    for (int j = 0; j < 8; ++j)
      w1f[t * 8 + j] = f2bf(W1[(k0 + j) * HH + col]);
  }
  if (t < 8 * 8 * 64) {
    int lane = t & 63, ks = (t >> 6) & 7, ct = t >> 9;
    int col = ct * 16 + (lane & 15);
    int k0 = ks * 32 + (lane >> 4) * 8;
    for (int j = 0; j < 8; ++j)
      w2f[t * 8 + j] = f2bf(W2[(k0 + j) * DO + col]);
  }
}

// Zero bcnt[0..NBINS] (incl. spill counter at NBINS) with agent-scope stores.
__global__ void zero_cnt_kernel(int* __restrict__ bcnt) {
  int i = blockIdx.x * 256 + threadIdx.x;
  if (i <= NBINS) ATOMIC_ST(&bcnt[i], 0);
}

// Pass A: sequential edge read -> bf16 -> APPEND to the receiver's bin.
// HALF-WAVE PER EDGE (512B coalesced read, 256B aligned write at the bin
// tail). 1564 append regions -> near-streaming write page locality (vs the
// round-9/10 per-node scatter over 100K slots which ran ~1.5-4 TB/s).
__global__ __launch_bounds__(256) void bin_kernel(
    const float4* __restrict__ edge4, const int* __restrict__ recv,
    int* __restrict__ bcnt, unsigned short* __restrict__ binpay,
    int* __restrict__ bin_nid, int* __restrict__ spill_node,
    unsigned short* __restrict__ spill_data) {
  int gtid = blockIdx.x * 256 + threadIdx.x;
  int e = gtid >> 5;                 // grid sized exactly: e < Bb*Ee
  int hl = threadIdx.x & 31;
  int b = (e >= Ee) ? 1 : 0;
  int r = recv[e];
  int bin = b * BINS_B + (r >> 6);

  float4 v = edge4[(long)e * 32 + hl];
  ushort4 o;
  o.x = f2bf(v.x); o.y = f2bf(v.y); o.z = f2bf(v.z); o.w = f2bf(v.w);

  int pos;
  if (hl == 0) pos = atomicAdd(&bcnt[bin], 1);
  pos = __shfl(pos, threadIdx.x & 32);  // broadcast within half-wave

  if (pos < CAPB) {
    reinterpret_cast<ushort4*>(binpay)[((long)bin * CAPB + pos) * 32 + hl] = o;
    if (hl == 0) bin_nid[(long)bin * CAPB + pos] = r & 63;  // local node id
  } else {  // ~never (P < 1e-16 total)
    int s;
    if (hl == 0) s = atomicAdd(&bcnt[NBINS], 1);
    s = __shfl(s, threadIdx.x & 32);
    if (s < SPILL_MAX) {
      if (hl == 0) spill_node[s] = b * Nn + r;
      reinterpret_cast<ushort4*>(spill_data)[(long)s * 32 + hl] = o;
    }
  }
}

// Pass B: block per bin. Reads the bin's payload FULLY CONTIGUOUSLY
// (avg 168KB streaming), accumulates into a 64x128 f32 LDS tile via
// ds_add_f32 (collisions between entries of the same node are handled by
// the atomic; order-jitter is ~1e-6 rel). 32KB LDS -> 5 blocks/CU; 8-deep
// entry unroll -> ~10MB in flight device-wide. Writes bf16 aggb once.
__global__ __launch_bounds__(256) void reduce_kernel(
    const unsigned short* __restrict__ binpay, const int* __restrict__ bin_nid,
    const int* __restrict__ bcnt, const int* __restrict__ spill_node,
    const unsigned short* __restrict__ spill_data, unsigned short* __restrict__ aggb) {
  __shared__ float sacc[64 * 128];  // 32KB
  const int tid = threadIdx.x;
  const int bin = blockIdx.x;
  const int b = (bin >= BINS_B) ? 1 : 0;
  const int binl = bin - b * BINS_B;
  const int node0 = binl * 64;
  const int nnodes = min(64, Nn - node0);

  for (int i = tid; i < 64 * 128; i += 256) sacc[i] = 0.f;
  __syncthreads();

  {
    const int wv = tid >> 6;
    const int lane = tid & 63;           // lane covers bf16 cols 2*lane, 2*lane+1
    const int n_e = min(bcnt[bin], CAPB);
    const ushort2* pay2 = reinterpret_cast<const ushort2*>(binpay + (long)bin * CAPB * DE);
    const int* nids = bin_nid + (long)bin * CAPB;
    for (int i0 = wv * 8; i0 < n_e; i0 += 32) {
      int m = min(8, n_e - i0);
      if (m == 8) {
        ushort2 q[8]; int nd[8];
#pragma unroll
        for (int k = 0; k < 8; ++k) {
          q[k] = pay2[(long)(i0 + k) * 64 + lane];
          nd[k] = nids[i0 + k];
        }
#pragma unroll
        for (int k = 0; k < 8; ++k) {
          atomicAdd(&sacc[nd[k] * 128 + lane * 2], bf2f(q[k].x));
          atomicAdd(&sacc[nd[k] * 128 + lane * 2 + 1], bf2f(q[k].y));
        }
      } else {
        for (int k = 0; k < m; ++k) {
          ushort2 q = pay2[(long)(i0 + k) * 64 + lane];
          int nd = nids[i0 + k];
          atomicAdd(&sacc[nd * 128 + lane * 2], bf2f(q.x));
          atomicAdd(&sacc[nd * 128 + lane * 2 + 1], bf2f(q.y));
        }
      }
    }
  }

  // rare spill fix-up (bin overflow; normally bcnt[NBINS]==0). Wave 0 only.
  {
    int sn = min(bcnt[NBINS], SPILL_MAX);
    if (sn > 0 && tid < 64) {
      int lane = tid;
      int glo = b * Nn + node0;
      for (int s = 0; s < sn; ++s) {
        int g = spill_node[s];
        if (g >= glo && g < glo + nnodes) {
          ushort2 q = reinterpret_cast<const ushort2*>(spill_data + (long)s * DE)[lane];
          atomicAdd(&sacc[(g - glo) * 128 + lane * 2], bf2f(q.x));
          atomicAdd(&sacc[(g - glo) * 128 + lane * 2 + 1], bf2f(q.y));
        }
      }
    }
  }
  __syncthreads();

  // writeback: half-wave per node row, bf16
  {
    const int hw = tid >> 5;
    const int hl = tid & 31;
    for (int nl = hw; nl < nnodes; nl += 8) {
      long g = (long)b * Nn + node0 + nl;
      ushort4 o;
      o.x = f2bf(sacc[nl * 128 + hl * 4 + 0]);
      o.y = f2bf(sacc[nl * 128 + hl * 4 + 1]);
      o.z = f2bf(sacc[nl * 128 + hl * 4 + 2]);
      o.w = f2bf(sacc[nl * 128 + hl * 4 + 3]);
      reinterpret_cast<ushort4*>(aggb)[g * 32 + hl] = o;
    }
  }
}

// MLP (round-8-proven): per block, 64 nodes. vtin=[aggb(bf16)|node(f32->bf16)]
// in LDS (XOR-swizzled), GEMM1 -> relu -> h in LDS -> GEMM2 -> out f32.
__global__ __launch_bounds__(256, 2) void mlp_kernel(
    const unsigned short* __restrict__ aggb, const float* __restrict__ node,
    const unsigned short* __restrict__ w1f, const unsigned short* __restrict__ w2f,
    const float* __restrict__ b1, const float* __restrict__ b2,
    float* __restrict__ out) {
  __shared__ __align__(16) char lds[64 * 512];  // 64 rows x 256 cols bf16
  const int tid = threadIdx.x;
  const int lane = tid & 63;
  const int wv = tid >> 6;
  const int blk = blockIdx.x;
  const int b = blk / TILES;
  const int tile = blk - b * TILES;
  const int row0 = tile * 64;
  const int rows = min(64, Nn - row0);

  // ---- stage vtin: agg half is already bf16; node half converts ----
#pragma unroll
  for (int ii = 0; ii < 8; ++ii) {  // cols 0..127 from aggb
    int idx = ii * 256 + tid;
    int row = idx >> 5;
    int c4 = idx & 31;
    ushort4 p = make_ushort4(0, 0, 0, 0);
    if (row < rows)
      p = reinterpret_cast<const ushort4*>(aggb)[((long)b * Nn + row0 + row) * 32 + c4];
    int byte = row * 512 + ((c4 * 8) ^ ((row & 7) << 4));
    *reinterpret_cast<ushort4*>(&lds[byte]) = p;
  }
#pragma unroll
  for (int ii = 0; ii < 8; ++ii) {  // cols 128..255 from node_data
    int idx = ii * 256 + tid;
    int row = idx >> 5;
    int c4 = idx & 31;
    float4 v = make_float4(0.f, 0.f, 0.f, 0.f);
    if (row < rows)
      v = reinterpret_cast<const float4*>(node)[((long)b * Nn + row0 + row) * 32 + c4];
    ushort4 p;
    p.x = f2bf(v.x); p.y = f2bf(v.y); p.z = f2bf(v.z); p.w = f2bf(v.w);
    int byte = row * 512 + ((256 + c4 * 8) ^ ((row & 7) << 4));
    *reinterpret_cast<ushort4*>(&lds[byte]) = p;
  }
  __syncthreads();

  // ---- GEMM1: h = relu(vtin @ W1 + b1) ----
  f32x4 acc[16];
#pragma unroll
  for (int ct = 0; ct < 16; ++ct) acc[ct] = (f32x4){0.f, 0.f, 0.f, 0.f};
  const int arow = wv * 16 + (lane & 15);
  const int abase = arow * 512;
  const int aswz = (arow & 7) << 4;
  const int koff = (lane >> 4) * 16;
#pragma unroll
  for (int ks = 0; ks < 8; ++ks) {
    short8 a = *reinterpret_cast<const short8*>(&lds[abase + ((ks * 64 + koff) ^ aswz)]);
#pragma unroll
    for (int ct = 0; ct < 16; ++ct) {
      short8 bf = *reinterpret_cast<const short8*>(w1f + ((ct * 8 + ks) * 64 + lane) * 8);
      acc[ct] = __builtin_amdgcn_mfma_f32_16x16x32_bf16(a, bf, acc[ct], 0, 0, 0);
    }
  }
  __syncthreads();  // all waves done reading vtin before overwrite

  // ---- bias + relu, write h (bf16, swizzled) ----
  {
    const int colb = lane & 15;
    const int rb = wv * 16 + (lane >> 4) * 4;
#pragma unroll
    for (int ct = 0; ct < 16; ++ct) {
      float bias = b1[ct * 16 + colb];
#pragma unroll
      for (int j = 0; j < 4; ++j) {
        float hv = acc[ct][j] + bias;
        hv = hv > 0.f ? hv : 0.f;
        int row = rb + j;
        int byte = row * 512 + (((ct * 16 + colb) * 2) ^ ((row & 7) << 4));
        *reinterpret_cast<unsigned short*>(&lds[byte]) = f2bf(hv);
      }
    }
  }
  __syncthreads();

  // ---- GEMM2: out = h @ W2 + b2 ----
  f32x4 acc2[8];
#pragma unroll
  for (int ct = 0; ct < 8; ++ct) acc2[ct] = (f32x4){0.f, 0.f, 0.f, 0.f};
#pragma unroll
  for (int ks = 0; ks < 8; ++ks) {
    short8 a = *reinterpret_cast<const short8*>(&lds[abase + ((ks * 64 + koff) ^ aswz)]);
#pragma unroll
    for (int ct = 0; ct < 8; ++ct) {
      short8 bf = *reinterpret_cast<const short8*>(w2f + ((ct * 8 + ks) * 64 + lane) * 8);
      acc2[ct] = __builtin_amdgcn_mfma_f32_16x16x32_bf16(a, bf, acc2[ct], 0, 0, 0);
    }
  }
  {
    const int colb = lane & 15;
    const int rb = wv * 16 + (lane >> 4) * 4;
#pragma unroll
    for (int ct = 0; ct < 8; ++ct) {
      float bias = b2[ct * 16 + colb];
#pragma unroll
      for (int j = 0; j < 4; ++j) {
        int r = rb + j;
        if (r < rows)
          out[((long)b * Nn + row0 + r) * DO + ct * 16 + colb] = acc2[ct][j] + bias;
      }
    }
  }
}

extern "C" void kernel_launch(void* const* d_in, const int* in_sizes, int n_in,
                              void* d_out, int out_size, void* d_ws, size_t ws_size,
                              hipStream_t stream) {
  const float* edge = (const float*)d_in[0];
  const float* node = (const float*)d_in[1];
  const float* W1   = (const float*)d_in[2];
  const float* b1   = (const float*)d_in[3];
  const float* W2   = (const float*)d_in[4];
  const float* b2   = (const float*)d_in[5];
  const int*   recv = (const int*)d_in[6];
  float* out = (float*)d_out;

  char* ws = (char*)d_ws;
  size_t off = 0;
  unsigned short* w1f = (unsigned short*)(ws + off); off += 131072;
  unsigned short* w2f = (unsigned short*)(ws + off); off += 65536;
  int* bcnt = (int*)(ws + off); off += 8192;                         // (NBINS+1)*4 padded
  int* spill_node = (int*)(ws + off); off += SPILL_MAX * 4;          // 262,144
  unsigned short* spill_data = (unsigned short*)(ws + off); off += (size_t)SPILL_MAX * DE * 2;  // 16.8 MB
  unsigned short* aggb = (unsigned short*)(ws + off); off += (size_t)Bb * Nn * DE * 2;  // 25.6 MB
  int* bin_nid = (int*)(ws + off); off += (size_t)NBINS * CAPB * 4;  // 5.6 MB
  unsigned short* binpay = (unsigned short*)(ws + off);              // NBINS*CAPB*256B = 358.7 MB

  wconv_kernel<<<32, 256, 0, stream>>>(W1, W2, w1f, w2f);
  zero_cnt_kernel<<<(NBINS + 256) / 256, 256, 0, stream>>>(bcnt);
  bin_kernel<<<Bb * Ee / 8, 256, 0, stream>>>((const float4*)edge, recv, bcnt,
                                              binpay, bin_nid, spill_node, spill_data);
  reduce_kernel<<<NBINS, 256, 0, stream>>>(binpay, bin_nid, bcnt,
                                           spill_node, spill_data, aggb);
  mlp_kernel<<<Bb * TILES, 256, 0, stream>>>(aggb, node, w1f, w2f, b1, b2, out);
}

// Round 12
// 599.447 us; speedup vs baseline: 2.1387x; 2.1387x over previous
//
#include <hip/hip_runtime.h>

#define Bb 2
#define Nn 50000
#define Ee 512000
#define DE 128
#define HH 256
#define DO 128
#define TILES 782        // ceil(50000/64)
#define BINS_B 782       // bins per batch, 64 nodes each
#define NBINS (Bb * BINS_B)
#define CAPB 896         // bin capacity; Poisson(655)+9.4sigma
#define NCAP 40          // per-node list capacity; P(deg>40|Poisson(10.24)) ~ 1e-11
#define SPILL_MAX 65536

typedef __attribute__((ext_vector_type(8))) short short8;
typedef __attribute__((ext_vector_type(4))) float f32x4;

// Agent-scope atomic store: lay down the zeros that later atomicAdds RMW
// (round-3: plain-stored zeros + cross-kernel atomic RMW diverged in replay).
#define ATOMIC_ST(p, v) __hip_atomic_store((p), (v), __ATOMIC_RELAXED, __HIP_MEMORY_SCOPE_AGENT)

// f32 -> bf16 round-to-nearest-even (data has no NaN/Inf)
static __device__ __forceinline__ unsigned short f2bf(float f) {
  union { float f; unsigned int u; } x; x.f = f;
  return (unsigned short)((x.u + 0x7FFFu + ((x.u >> 16) & 1u)) >> 16);
}
// bf16 -> f32
static __device__ __forceinline__ float bf2f(unsigned short h) {
  union { unsigned int u; float f; } x; x.u = ((unsigned int)h) << 16;
  return x.f;
}

// Pre-convert W1/W2 into bf16 MFMA B-fragment order (one dwordx4 per frag).
__global__ void wconv_kernel(const float* __restrict__ W1, const float* __restrict__ W2,
                             unsigned short* __restrict__ w1f, unsigned short* __restrict__ w2f) {
  int t = blockIdx.x * 256 + threadIdx.x;
  if (t < 16 * 8 * 64) {
    int lane = t & 63, ks = (t >> 6) & 7, ct = t >> 9;
    int col = ct * 16 + (lane & 15);
    int k0 = ks * 32 + (lane >> 4) * 8;
    for (int j = 0; j < 8; ++j)
      w1f[t * 8 + j] = f2bf(W1[(k0 + j) * HH + col]);
  }
  if (t < 8 * 8 * 64) {
    int lane = t & 63, ks = (t >> 6) & 7, ct = t >> 9;
    int col = ct * 16 + (lane & 15);
    int k0 = ks * 32 + (lane >> 4) * 8;
    for (int j = 0; j < 8; ++j)
      w2f[t * 8 + j] = f2bf(W2[(k0 + j) * DO + col]);
  }
}

// Zero bcnt[0..NBINS] (incl. spill counter at NBINS) with agent-scope stores.
__global__ void zero_cnt_kernel(int* __restrict__ bcnt) {
  int i = blockIdx.x * 256 + threadIdx.x;
  if (i <= NBINS) ATOMIC_ST(&bcnt[i], 0);
}

// Pass A: sequential edge read -> bf16 -> APPEND to the receiver's bin.
// HALF-WAVE PER EDGE (512B coalesced read, 256B aligned write at the bin
// tail). 1564 append regions -> near-streaming write page locality.
__global__ __launch_bounds__(256) void bin_kernel(
    const float4* __restrict__ edge4, const int* __restrict__ recv,
    int* __restrict__ bcnt, unsigned short* __restrict__ binpay,
    int* __restrict__ bin_nid, int* __restrict__ spill_node,
    unsigned short* __restrict__ spill_data) {
  int gtid = blockIdx.x * 256 + threadIdx.x;
  int e = gtid >> 5;                 // grid sized exactly: e < Bb*Ee
  int hl = threadIdx.x & 31;
  int b = (e >= Ee) ? 1 : 0;
  int r = recv[e];
  int bin = b * BINS_B + (r >> 6);

  float4 v = edge4[(long)e * 32 + hl];
  ushort4 o;
  o.x = f2bf(v.x); o.y = f2bf(v.y); o.z = f2bf(v.z); o.w = f2bf(v.w);

  int pos;
  if (hl == 0) pos = atomicAdd(&bcnt[bin], 1);
  pos = __shfl(pos, threadIdx.x & 32);  // broadcast within half-wave

  if (pos < CAPB) {
    reinterpret_cast<ushort4*>(binpay)[((long)bin * CAPB + pos) * 32 + hl] = o;
    if (hl == 0) bin_nid[(long)bin * CAPB + pos] = r & 63;  // local node id
  } else {  // ~never (P < 1e-16 total)
    int s;
    if (hl == 0) s = atomicAdd(&bcnt[NBINS], 1);
    s = __shfl(s, threadIdx.x & 32);
    if (s < SPILL_MAX) {
      if (hl == 0) spill_node[s] = b * Nn + r;
      reinterpret_cast<ushort4*>(spill_data)[(long)s * 32 + hl] = o;
    }
  }
}

// Pass B (atomic-free; round-11 post-mortem: per-entry LDS f32 atomics =
// 262M serialized RMWs = 754us). Phase 1: build per-node entry-id lists in
// LDS (655 int-LDS-atomics on 64 counters). Phase 2: HALF-WAVE OWNS A NODE —
// read its ~10 ids (LDS broadcast), gather 256B payload rows (coalesced,
// 4-deep ILP, page-local within the bin's 168KB), accumulate in REGISTERS,
// write bf16 aggb once. No f32 atomics anywhere.
__global__ __launch_bounds__(256) void reduce_kernel(
    const unsigned short* __restrict__ binpay, const int* __restrict__ bin_nid,
    const int* __restrict__ bcnt, const int* __restrict__ spill_node,
    const unsigned short* __restrict__ spill_data, unsigned short* __restrict__ aggb) {
  __shared__ int lcnt[64];
  __shared__ unsigned short lid[64 * NCAP];  // 5.1 KB
  const int tid = threadIdx.x;
  const int bin = blockIdx.x;
  const int b = (bin >= BINS_B) ? 1 : 0;
  const int binl = bin - b * BINS_B;
  const int node0 = binl * 64;
  const int nnodes = min(64, Nn - node0);
  const int n_e = min(bcnt[bin], CAPB);
  const int* __restrict__ nids = bin_nid + (long)bin * CAPB;

  if (tid < 64) lcnt[tid] = 0;
  __syncthreads();
  // ---- Phase 1: entry-id lists ----
  for (int i = tid; i < n_e; i += 256) {
    int nd = nids[i];
    int pos = atomicAdd(&lcnt[nd], 1);
    if (pos < NCAP) lid[nd * NCAP + pos] = (unsigned short)i;
  }
  __syncthreads();

  // ---- Phase 2: per-node register accumulation ----
  const int hw = tid >> 5;   // half-wave 0..7
  const int hl = tid & 31;   // lane: ushort4 = cols hl*4..hl*4+3
  const ushort4* __restrict__ pay4 =
      reinterpret_cast<const ushort4*>(binpay + (long)bin * CAPB * DE);
  const int sn = min(bcnt[NBINS], SPILL_MAX);

  for (int nl = hw; nl < nnodes; nl += 8) {
    float a0 = 0.f, a1 = 0.f, a2 = 0.f, a3 = 0.f;
    int deg0 = lcnt[nl];
    int deg = min(deg0, NCAP);
    const unsigned short* ids = &lid[nl * NCAP];

    if (deg0 <= NCAP) {
      int i = 0;
      for (; i + 4 <= deg; i += 4) {  // 4 rows in flight
        ushort4 q0 = pay4[(int)ids[i + 0] * 32 + hl];
        ushort4 q1 = pay4[(int)ids[i + 1] * 32 + hl];
        ushort4 q2 = pay4[(int)ids[i + 2] * 32 + hl];
        ushort4 q3 = pay4[(int)ids[i + 3] * 32 + hl];
        a0 += (bf2f(q0.x) + bf2f(q1.x)) + (bf2f(q2.x) + bf2f(q3.x));
        a1 += (bf2f(q0.y) + bf2f(q1.y)) + (bf2f(q2.y) + bf2f(q3.y));
        a2 += (bf2f(q0.z) + bf2f(q1.z)) + (bf2f(q2.z) + bf2f(q3.z));
        a3 += (bf2f(q0.w) + bf2f(q1.w)) + (bf2f(q2.w) + bf2f(q3.w));
      }
      for (; i < deg; ++i) {
        ushort4 q = pay4[(int)ids[i] * 32 + hl];
        a0 += bf2f(q.x); a1 += bf2f(q.y); a2 += bf2f(q.z); a3 += bf2f(q.w);
      }
    } else {  // list overflowed (~1e-11): rescan the whole bin, sum all matches
      for (int s = 0; s < n_e; ++s) {
        if (nids[s] == nl) {
          ushort4 q = pay4[s * 32 + hl];
          a0 += bf2f(q.x); a1 += bf2f(q.y); a2 += bf2f(q.z); a3 += bf2f(q.w);
        }
      }
    }

    if (sn > 0) {  // dormant bin-overflow fix-up
      int g = b * Nn + node0 + nl;
      for (int s = 0; s < sn; ++s) {
        if (spill_node[s] == g) {
          ushort4 q = reinterpret_cast<const ushort4*>(spill_data + (long)s * DE)[hl];
          a0 += bf2f(q.x); a1 += bf2f(q.y); a2 += bf2f(q.z); a3 += bf2f(q.w);
        }
      }
    }

    long g = (long)b * Nn + node0 + nl;
    ushort4 o;
    o.x = f2bf(a0); o.y = f2bf(a1); o.z = f2bf(a2); o.w = f2bf(a3);
    reinterpret_cast<ushort4*>(aggb)[g * 32 + hl] = o;
  }
}

// MLP (round-8-proven): per block, 64 nodes. vtin=[aggb(bf16)|node(f32->bf16)]
// in LDS (XOR-swizzled), GEMM1 -> relu -> h in LDS -> GEMM2 -> out f32.
__global__ __launch_bounds__(256, 2) void mlp_kernel(
    const unsigned short* __restrict__ aggb, const float* __restrict__ node,
    const unsigned short* __restrict__ w1f, const unsigned short* __restrict__ w2f,
    const float* __restrict__ b1, const float* __restrict__ b2,
    float* __restrict__ out) {
  __shared__ __align__(16) char lds[64 * 512];  // 64 rows x 256 cols bf16
  const int tid = threadIdx.x;
  const int lane = tid & 63;
  const int wv = tid >> 6;
  const int blk = blockIdx.x;
  const int b = blk / TILES;
  const int tile = blk - b * TILES;
  const int row0 = tile * 64;
  const int rows = min(64, Nn - row0);

  // ---- stage vtin: agg half is already bf16; node half converts ----
#pragma unroll
  for (int ii = 0; ii < 8; ++ii) {  // cols 0..127 from aggb
    int idx = ii * 256 + tid;
    int row = idx >> 5;
    int c4 = idx & 31;
    ushort4 p = make_ushort4(0, 0, 0, 0);
    if (row < rows)
      p = reinterpret_cast<const ushort4*>(aggb)[((long)b * Nn + row0 + row) * 32 + c4];
    int byte = row * 512 + ((c4 * 8) ^ ((row & 7) << 4));
    *reinterpret_cast<ushort4*>(&lds[byte]) = p;
  }
#pragma unroll
  for (int ii = 0; ii < 8; ++ii) {  // cols 128..255 from node_data
    int idx = ii * 256 + tid;
    int row = idx >> 5;
    int c4 = idx & 31;
    float4 v = make_float4(0.f, 0.f, 0.f, 0.f);
    if (row < rows)
      v = reinterpret_cast<const float4*>(node)[((long)b * Nn + row0 + row) * 32 + c4];
    ushort4 p;
    p.x = f2bf(v.x); p.y = f2bf(v.y); p.z = f2bf(v.z); p.w = f2bf(v.w);
    int byte = row * 512 + ((256 + c4 * 8) ^ ((row & 7) << 4));
    *reinterpret_cast<ushort4*>(&lds[byte]) = p;
  }
  __syncthreads();

  // ---- GEMM1: h = relu(vtin @ W1 + b1) ----
  f32x4 acc[16];
#pragma unroll
  for (int ct = 0; ct < 16; ++ct) acc[ct] = (f32x4){0.f, 0.f, 0.f, 0.f};
  const int arow = wv * 16 + (lane & 15);
  const int abase = arow * 512;
  const int aswz = (arow & 7) << 4;
  const int koff = (lane >> 4) * 16;
#pragma unroll
  for (int ks = 0; ks < 8; ++ks) {
    short8 a = *reinterpret_cast<const short8*>(&lds[abase + ((ks * 64 + koff) ^ aswz)]);
#pragma unroll
    for (int ct = 0; ct < 16; ++ct) {
      short8 bf = *reinterpret_cast<const short8*>(w1f + ((ct * 8 + ks) * 64 + lane) * 8);
      acc[ct] = __builtin_amdgcn_mfma_f32_16x16x32_bf16(a, bf, acc[ct], 0, 0, 0);
    }
  }
  __syncthreads();  // all waves done reading vtin before overwrite

  // ---- bias + relu, write h (bf16, swizzled) ----
  {
    const int colb = lane & 15;
    const int rb = wv * 16 + (lane >> 4) * 4;
#pragma unroll
    for (int ct = 0; ct < 16; ++ct) {
      float bias = b1[ct * 16 + colb];
#pragma unroll
      for (int j = 0; j < 4; ++j) {
        float hv = acc[ct][j] + bias;
        hv = hv > 0.f ? hv : 0.f;
        int row = rb + j;
        int byte = row * 512 + (((ct * 16 + colb) * 2) ^ ((row & 7) << 4));
        *reinterpret_cast<unsigned short*>(&lds[byte]) = f2bf(hv);
      }
    }
  }
  __syncthreads();

  // ---- GEMM2: out = h @ W2 + b2 ----
  f32x4 acc2[8];
#pragma unroll
  for (int ct = 0; ct < 8; ++ct) acc2[ct] = (f32x4){0.f, 0.f, 0.f, 0.f};
#pragma unroll
  for (int ks = 0; ks < 8; ++ks) {
    short8 a = *reinterpret_cast<const short8*>(&lds[abase + ((ks * 64 + koff) ^ aswz)]);
#pragma unroll
    for (int ct = 0; ct < 8; ++ct) {
      short8 bf = *reinterpret_cast<const short8*>(w2f + ((ct * 8 + ks) * 64 + lane) * 8);
      acc2[ct] = __builtin_amdgcn_mfma_f32_16x16x32_bf16(a, bf, acc2[ct], 0, 0, 0);
    }
  }
  {
    const int colb = lane & 15;
    const int rb = wv * 16 + (lane >> 4) * 4;
#pragma unroll
    for (int ct = 0; ct < 8; ++ct) {
      float bias = b2[ct * 16 + colb];
#pragma unroll
      for (int j = 0; j < 4; ++j) {
        int r = rb + j;
        if (r < rows)
          out[((long)b * Nn + row0 + r) * DO + ct * 16 + colb] = acc2[ct][j] + bias;
      }
    }
  }
}

extern "C" void kernel_launch(void* const* d_in, const int* in_sizes, int n_in,
                              void* d_out, int out_size, void* d_ws, size_t ws_size,
                              hipStream_t stream) {
  const float* edge = (const float*)d_in[0];
  const float* node = (const float*)d_in[1];
  const float* W1   = (const float*)d_in[2];
  const float* b1   = (const float*)d_in[3];
  const float* W2   = (const float*)d_in[4];
  const float* b2   = (const float*)d_in[5];
  const int*   recv = (const int*)d_in[6];
  float* out = (float*)d_out;

  char* ws = (char*)d_ws;
  size_t off = 0;
  unsigned short* w1f = (unsigned short*)(ws + off); off += 131072;
  unsigned short* w2f = (unsigned short*)(ws + off); off += 65536;
  int* bcnt = (int*)(ws + off); off += 8192;                         // (NBINS+1)*4 padded
  int* spill_node = (int*)(ws + off); off += SPILL_MAX * 4;          // 262,144
  unsigned short* spill_data = (unsigned short*)(ws + off); off += (size_t)SPILL_MAX * DE * 2;  // 16.8 MB
  unsigned short* aggb = (unsigned short*)(ws + off); off += (size_t)Bb * Nn * DE * 2;  // 25.6 MB
  int* bin_nid = (int*)(ws + off); off += (size_t)NBINS * CAPB * 4;  // 5.6 MB
  unsigned short* binpay = (unsigned short*)(ws + off);              // NBINS*CAPB*256B = 358.7 MB

  wconv_kernel<<<32, 256, 0, stream>>>(W1, W2, w1f, w2f);
  zero_cnt_kernel<<<(NBINS + 256) / 256, 256, 0, stream>>>(bcnt);
  bin_kernel<<<Bb * Ee / 8, 256, 0, stream>>>((const float4*)edge, recv, bcnt,
                                              binpay, bin_nid, spill_node, spill_data);
  reduce_kernel<<<NBINS, 256, 0, stream>>>(binpay, bin_nid, bcnt,
                                           spill_node, spill_data, aggb);
  mlp_kernel<<<Bb * TILES, 256, 0, stream>>>(aggb, node, w1f, w2f, b1, b2, out);
}

// Round 13
// 468.736 us; speedup vs baseline: 2.7350x; 1.2789x over previous
//
#include <hip/hip_runtime.h>

#define Bb 2
#define Nn 50000
#define Ee 512000
#define DE 128
#define HH 256
#define DO 128
#define TILES 782        // ceil(50000/64)
#define CAP1 16          // tier-1 slots/node (dense-read); P(deg>16|Poisson(10.24)) ~ 3.2%
#define CAP2 16          // tier-2 slots/node (prefix-read, deg 17..32)
#define NCNT (Bb * Nn)   // 100,000 nodes; cnt[NCNT] is the spill counter
#define SPILL_MAX 4096   // deg>32: P ~ 3e-8 per node -> essentially never

typedef __attribute__((ext_vector_type(8))) short short8;
typedef __attribute__((ext_vector_type(4))) float f32x4;

// Agent-scope atomic store: lay down the zeros that later atomicAdds RMW
// (round-3: plain-stored zeros + cross-kernel atomic RMW diverged in replay).
#define ATOMIC_ST(p, v) __hip_atomic_store((p), (v), __ATOMIC_RELAXED, __HIP_MEMORY_SCOPE_AGENT)

// f32 -> bf16 round-to-nearest-even (data has no NaN/Inf)
static __device__ __forceinline__ unsigned short f2bf(float f) {
  union { float f; unsigned int u; } x; x.f = f;
  return (unsigned short)((x.u + 0x7FFFu + ((x.u >> 16) & 1u)) >> 16);
}
// bf16 -> f32
static __device__ __forceinline__ float bf2f(unsigned short h) {
  union { unsigned int u; float f; } x; x.u = ((unsigned int)h) << 16;
  return x.f;
}

// Pre-convert W1/W2 into bf16 MFMA B-fragment order (one dwordx4 per frag).
__global__ void wconv_kernel(const float* __restrict__ W1, const float* __restrict__ W2,
                             unsigned short* __restrict__ w1f, unsigned short* __restrict__ w2f) {
  int t = blockIdx.x * 256 + threadIdx.x;
  if (t < 16 * 8 * 64) {
    int lane = t & 63, ks = (t >> 6) & 7, ct = t >> 9;
    int col = ct * 16 + (lane & 15);
    int k0 = ks * 32 + (lane >> 4) * 8;
    for (int j = 0; j < 8; ++j)
      w1f[t * 8 + j] = f2bf(W1[(k0 + j) * HH + col]);
  }
  if (t < 8 * 8 * 64) {
    int lane = t & 63, ks = (t >> 6) & 7, ct = t >> 9;
    int col = ct * 16 + (lane & 15);
    int k0 = ks * 32 + (lane >> 4) * 8;
    for (int j = 0; j < 8; ++j)
      w2f[t * 8 + j] = f2bf(W2[(k0 + j) * DO + col]);
  }
}

// Zero cnt[0..NCNT] with AGENT-scope atomic stores.
__global__ void zero_cnt_kernel(int* __restrict__ cnt) {
  int i = blockIdx.x * 256 + threadIdx.x;
  if (i <= NCNT) ATOMIC_ST(&cnt[i], 0);
}

// Sequential-read / scattered-full-line-write placement (round-9-proven 4.1
// TB/s pattern: 100K cool counters ~10 RMW each; round-12's 1.5K hot counters
// bounced cache lines across XCDs and halved throughput). HALF-WAVE PER EDGE:
// 512B coalesced f32 read -> bf16 -> one 256B full-line slot write. Slot
// position encodes the node -> no nid side-array. deg 17..32 -> tier-2 array;
// deg>32 -> spill list (~never).
__global__ __launch_bounds__(256) void fill_place_kernel(
    const float4* __restrict__ edge4, const int* __restrict__ recv,
    int* __restrict__ cnt, unsigned short* __restrict__ pad1,
    unsigned short* __restrict__ pad2, int* __restrict__ spill_node,
    unsigned short* __restrict__ spill_data) {
  int gtid = blockIdx.x * 256 + threadIdx.x;
  int e = gtid >> 5;                 // grid sized exactly: e < Bb*Ee
  int hl = threadIdx.x & 31;
  int node = ((e >= Ee) ? Nn : 0) + recv[e];

  float4 v = edge4[(long)e * 32 + hl];
  ushort4 o;
  o.x = f2bf(v.x); o.y = f2bf(v.y); o.z = f2bf(v.z); o.w = f2bf(v.w);

  int pos;
  if (hl == 0) pos = atomicAdd(&cnt[node], 1);
  pos = __shfl(pos, threadIdx.x & 32);  // broadcast within half-wave

  if (pos < CAP1) {
    reinterpret_cast<ushort4*>(pad1)[((long)node * CAP1 + pos) * 32 + hl] = o;
  } else if (pos < CAP1 + CAP2) {
    reinterpret_cast<ushort4*>(pad2)[((long)node * CAP2 + (pos - CAP1)) * 32 + hl] = o;
  } else {  // ~never
    int s;
    if (hl == 0) s = atomicAdd(&cnt[NCNT], 1);
    s = __shfl(s, threadIdx.x & 32);
    if (s < SPILL_MAX) {
      if (hl == 0) spill_node[s] = node;
      reinterpret_cast<ushort4*>(spill_data)[(long)s * 32 + hl] = o;
    }
  }
}

// DENSE-STREAM reduce (round-12 lesson: strided 32%-dense reads ran 1.4 TB/s;
// pure sequential runs ~6). HALF-WAVE PER NODE reads ALL 16 tier-1 slots
// unconditionally (410MB perfectly sequential device-wide) and masks the adds
// with ?: selects (keeps loads unconditional & hoistable; garbage slots never
// enter arithmetic). Tier-2 prefix only for the 3.2% deg>16 nodes. No LDS,
// low VGPR -> 8 waves/SIMD.
__global__ __launch_bounds__(256, 8) void csr_sum_kernel(
    const unsigned short* __restrict__ pad1, const unsigned short* __restrict__ pad2,
    const int* __restrict__ cnt, const int* __restrict__ spill_node,
    const unsigned short* __restrict__ spill_data, unsigned short* __restrict__ aggb) {
  int node = (blockIdx.x * 256 + threadIdx.x) >> 5;
  int hl = threadIdx.x & 31;
  if (node >= NCNT) return;
  const int deg0 = cnt[node];
  const ushort4* b1 = reinterpret_cast<const ushort4*>(pad1 + (long)node * CAP1 * DE) + hl;

  float a0 = 0.f, a1 = 0.f, a2 = 0.f, a3 = 0.f;
#pragma unroll
  for (int i = 0; i < CAP1; i += 4) {  // 16 unconditional loads, 4KB/node stream
    ushort4 q0 = b1[(i + 0) * 32];
    ushort4 q1 = b1[(i + 1) * 32];
    ushort4 q2 = b1[(i + 2) * 32];
    ushort4 q3 = b1[(i + 3) * 32];
    a0 += (i + 0 < deg0) ? bf2f(q0.x) : 0.f;
    a1 += (i + 0 < deg0) ? bf2f(q0.y) : 0.f;
    a2 += (i + 0 < deg0) ? bf2f(q0.z) : 0.f;
    a3 += (i + 0 < deg0) ? bf2f(q0.w) : 0.f;
    a0 += (i + 1 < deg0) ? bf2f(q1.x) : 0.f;
    a1 += (i + 1 < deg0) ? bf2f(q1.y) : 0.f;
    a2 += (i + 1 < deg0) ? bf2f(q1.z) : 0.f;
    a3 += (i + 1 < deg0) ? bf2f(q1.w) : 0.f;
    a0 += (i + 2 < deg0) ? bf2f(q2.x) : 0.f;
    a1 += (i + 2 < deg0) ? bf2f(q2.y) : 0.f;
    a2 += (i + 2 < deg0) ? bf2f(q2.z) : 0.f;
    a3 += (i + 2 < deg0) ? bf2f(q2.w) : 0.f;
    a0 += (i + 3 < deg0) ? bf2f(q3.x) : 0.f;
    a1 += (i + 3 < deg0) ? bf2f(q3.y) : 0.f;
    a2 += (i + 3 < deg0) ? bf2f(q3.z) : 0.f;
    a3 += (i + 3 < deg0) ? bf2f(q3.w) : 0.f;
  }

  if (deg0 > CAP1) {  // 3.2% of nodes: small predicated prefix from tier-2
    const ushort4* b2 = reinterpret_cast<const ushort4*>(pad2 + (long)node * CAP2 * DE) + hl;
    int d2 = min(deg0 - CAP1, CAP2);
    for (int i = 0; i < d2; ++i) {
      ushort4 q = b2[i * 32];
      a0 += bf2f(q.x); a1 += bf2f(q.y); a2 += bf2f(q.z); a3 += bf2f(q.w);
    }
    if (deg0 > CAP1 + CAP2) {  // ~never
      int sn = min(cnt[NCNT], SPILL_MAX);
      for (int s = 0; s < sn; ++s) {
        if (spill_node[s] == node) {
          ushort4 q = reinterpret_cast<const ushort4*>(spill_data)[(long)s * 32 + hl];
          a0 += bf2f(q.x); a1 += bf2f(q.y); a2 += bf2f(q.z); a3 += bf2f(q.w);
        }
      }
    }
  }

  ushort4 o;
  o.x = f2bf(a0); o.y = f2bf(a1); o.z = f2bf(a2); o.w = f2bf(a3);
  reinterpret_cast<ushort4*>(aggb)[(long)node * 32 + hl] = o;
}

// MLP (round-8-proven): per block, 64 nodes. vtin=[aggb(bf16)|node(f32->bf16)]
// in LDS (XOR-swizzled), GEMM1 -> relu -> h in LDS -> GEMM2 -> out f32.
__global__ __launch_bounds__(256, 4) void mlp_kernel(
    const unsigned short* __restrict__ aggb, const float* __restrict__ node,
    const unsigned short* __restrict__ w1f, const unsigned short* __restrict__ w2f,
    const float* __restrict__ b1, const float* __restrict__ b2,
    float* __restrict__ out) {
  __shared__ __align__(16) char lds[64 * 512];  // 64 rows x 256 cols bf16
  const int tid = threadIdx.x;
  const int lane = tid & 63;
  const int wv = tid >> 6;
  const int blk = blockIdx.x;
  const int b = blk / TILES;
  const int tile = blk - b * TILES;
  const int row0 = tile * 64;
  const int rows = min(64, Nn - row0);

  // ---- stage vtin: agg half is already bf16; node half converts ----
#pragma unroll
  for (int ii = 0; ii < 8; ++ii) {  // cols 0..127 from aggb
    int idx = ii * 256 + tid;
    int row = idx >> 5;
    int c4 = idx & 31;
    ushort4 p = make_ushort4(0, 0, 0, 0);
    if (row < rows)
      p = reinterpret_cast<const ushort4*>(aggb)[((long)b * Nn + row0 + row) * 32 + c4];
    int byte = row * 512 + ((c4 * 8) ^ ((row & 7) << 4));
    *reinterpret_cast<ushort4*>(&lds[byte]) = p;
  }
#pragma unroll
  for (int ii = 0; ii < 8; ++ii) {  // cols 128..255 from node_data
    int idx = ii * 256 + tid;
    int row = idx >> 5;
    int c4 = idx & 31;
    float4 v = make_float4(0.f, 0.f, 0.f, 0.f);
    if (row < rows)
      v = reinterpret_cast<const float4*>(node)[((long)b * Nn + row0 + row) * 32 + c4];
    ushort4 p;
    p.x = f2bf(v.x); p.y = f2bf(v.y); p.z = f2bf(v.z); p.w = f2bf(v.w);
    int byte = row * 512 + ((256 + c4 * 8) ^ ((row & 7) << 4));
    *reinterpret_cast<ushort4*>(&lds[byte]) = p;
  }
  __syncthreads();

  // ---- GEMM1: h = relu(vtin @ W1 + b1) ----
  f32x4 acc[16];
#pragma unroll
  for (int ct = 0; ct < 16; ++ct) acc[ct] = (f32x4){0.f, 0.f, 0.f, 0.f};
  const int arow = wv * 16 + (lane & 15);
  const int abase = arow * 512;
  const int aswz = (arow & 7) << 4;
  const int koff = (lane >> 4) * 16;
#pragma unroll
  for (int ks = 0; ks < 8; ++ks) {
    short8 a = *reinterpret_cast<const short8*>(&lds[abase + ((ks * 64 + koff) ^ aswz)]);
#pragma unroll
    for (int ct = 0; ct < 16; ++ct) {
      short8 bf = *reinterpret_cast<const short8*>(w1f + ((ct * 8 + ks) * 64 + lane) * 8);
      acc[ct] = __builtin_amdgcn_mfma_f32_16x16x32_bf16(a, bf, acc[ct], 0, 0, 0);
    }
  }
  __syncthreads();  // all waves done reading vtin before overwrite

  // ---- bias + relu, write h (bf16, swizzled) ----
  {
    const int colb = lane & 15;
    const int rb = wv * 16 + (lane >> 4) * 4;
#pragma unroll
    for (int ct = 0; ct < 16; ++ct) {
      float bias = b1[ct * 16 + colb];
#pragma unroll
      for (int j = 0; j < 4; ++j) {
        float hv = acc[ct][j] + bias;
        hv = hv > 0.f ? hv : 0.f;
        int row = rb + j;
        int byte = row * 512 + (((ct * 16 + colb) * 2) ^ ((row & 7) << 4));
        *reinterpret_cast<unsigned short*>(&lds[byte]) = f2bf(hv);
      }
    }
  }
  __syncthreads();

  // ---- GEMM2: out = h @ W2 + b2 ----
  f32x4 acc2[8];
#pragma unroll
  for (int ct = 0; ct < 8; ++ct) acc2[ct] = (f32x4){0.f, 0.f, 0.f, 0.f};
#pragma unroll
  for (int ks = 0; ks < 8; ++ks) {
    short8 a = *reinterpret_cast<const short8*>(&lds[abase + ((ks * 64 + koff) ^ aswz)]);
#pragma unroll
    for (int ct = 0; ct < 8; ++ct) {
      short8 bf = *reinterpret_cast<const short8*>(w2f + ((ct * 8 + ks) * 64 + lane) * 8);
      acc2[ct] = __builtin_amdgcn_mfma_f32_16x16x32_bf16(a, bf, acc2[ct], 0, 0, 0);
    }
  }
  {
    const int colb = lane & 15;
    const int rb = wv * 16 + (lane >> 4) * 4;
#pragma unroll
    for (int ct = 0; ct < 8; ++ct) {
      float bias = b2[ct * 16 + colb];
#pragma unroll
      for (int j = 0; j < 4; ++j) {
        int r = rb + j;
        if (r < rows)
          out[((long)b * Nn + row0 + r) * DO + ct * 16 + colb] = acc2[ct][j] + bias;
      }
    }
  }
}

extern "C" void kernel_launch(void* const* d_in, const int* in_sizes, int n_in,
                              void* d_out, int out_size, void* d_ws, size_t ws_size,
                              hipStream_t stream) {
  const float* edge = (const float*)d_in[0];
  const float* node = (const float*)d_in[1];
  const float* W1   = (const float*)d_in[2];
  const float* b1   = (const float*)d_in[3];
  const float* W2   = (const float*)d_in[4];
  const float* b2   = (const float*)d_in[5];
  const int*   recv = (const int*)d_in[6];
  float* out = (float*)d_out;

  char* ws = (char*)d_ws;
  size_t off = 0;
  unsigned short* w1f = (unsigned short*)(ws + off); off += 131072;
  unsigned short* w2f = (unsigned short*)(ws + off); off += 65536;
  int* cnt = (int*)(ws + off); off += 400016;                        // (NCNT+1)*4 padded
  int* spill_node = (int*)(ws + off); off += SPILL_MAX * 4;          // 16,384
  unsigned short* spill_data = (unsigned short*)(ws + off); off += (size_t)SPILL_MAX * DE * 2;  // 1 MB
  unsigned short* aggb = (unsigned short*)(ws + off); off += (size_t)NCNT * DE * 2;  // 25.6 MB
  unsigned short* pad1 = (unsigned short*)(ws + off); off += (size_t)NCNT * CAP1 * DE * 2;  // 409.6 MB
  unsigned short* pad2 = (unsigned short*)(ws + off);                // 409.6 MB

  wconv_kernel<<<32, 256, 0, stream>>>(W1, W2, w1f, w2f);
  zero_cnt_kernel<<<(NCNT + 256) / 256, 256, 0, stream>>>(cnt);
  fill_place_kernel<<<Bb * Ee / 8, 256, 0, stream>>>((const float4*)edge, recv, cnt,
                                                     pad1, pad2, spill_node, spill_data);
  csr_sum_kernel<<<(NCNT * 32 + 255) / 256, 256, 0, stream>>>(pad1, pad2, cnt,
                                                              spill_node, spill_data, aggb);
  mlp_kernel<<<Bb * TILES, 256, 0, stream>>>(aggb, node, w1f, w2f, b1, b2, out);
}

// Round 14
// 350.638 us; speedup vs baseline: 3.6562x; 1.3368x over previous
//
#include <hip/hip_runtime.h>

#define Bb 2
#define Nn 50000
#define Ee 512000
#define DE 128
#define HH 256
#define DO 128
#define TILES32 1563     // ceil(50000/32)
#define CAP 48           // per-node edge-list capacity (Poisson(10.24) max deg ~35)
#define NCNT (Bb * Nn)   // 100,000 nodes; cnt[NCNT] is the spill counter
#define SPILL_MAX 65536

typedef __attribute__((ext_vector_type(8))) short short8;
typedef __attribute__((ext_vector_type(4))) float f32x4;

// Agent-scope atomic store: lay down the zeros that later atomicAdds RMW
// (round-3: plain-stored zeros + cross-kernel atomic RMW diverged in replay).
#define ATOMIC_ST(p, v) __hip_atomic_store((p), (v), __ATOMIC_RELAXED, __HIP_MEMORY_SCOPE_AGENT)

// f32 -> bf16 round-to-nearest-even (data has no NaN/Inf)
static __device__ __forceinline__ unsigned short f2bf(float f) {
  union { float f; unsigned int u; } x; x.f = f;
  return (unsigned short)((x.u + 0x7FFFu + ((x.u >> 16) & 1u)) >> 16);
}

// Init: W1/W2 -> bf16 MFMA B-fragment order, AND zero cnt[] (merged to save
// a launch). Fragment layout: frag(ct,ks): lane l holds col=ct*16+(l&15),
// k=ks*32+(l>>4)*8+j -> one dwordx4 per fragment load.
__global__ void init_kernel(const float* __restrict__ W1, const float* __restrict__ W2,
                            unsigned short* __restrict__ w1f, unsigned short* __restrict__ w2f,
                            int* __restrict__ cnt) {
  int t = blockIdx.x * 256 + threadIdx.x;
  if (t < 16 * 8 * 64) {
    int lane = t & 63, ks = (t >> 6) & 7, ct = t >> 9;
    int col = ct * 16 + (lane & 15);
    int k0 = ks * 32 + (lane >> 4) * 8;
    for (int j = 0; j < 8; ++j)
      w1f[t * 8 + j] = f2bf(W1[(k0 + j) * HH + col]);
  }
  if (t < 8 * 8 * 64) {
    int lane = t & 63, ks = (t >> 6) & 7, ct = t >> 9;
    int col = ct * 16 + (lane & 15);
    int k0 = ks * 32 + (lane >> 4) * 8;
    for (int j = 0; j < 8; ++j)
      w2f[t * 8 + j] = f2bf(W2[(k0 + j) * DO + col]);
  }
  if (t <= NCNT) ATOMIC_ST(&cnt[t], 0);
}

// Build per-node edge lists: one int atomic per edge; plain ids stores
// (round-2/5-proven visible to the next dispatch's plain loads).
__global__ void fill_kernel(const int* __restrict__ recv, int* __restrict__ cnt,
                            int* __restrict__ ids, int* __restrict__ spill) {
  int i = blockIdx.x * 256 + threadIdx.x;  // grid sized to exactly Bb*Ee
  if (i >= Bb * Ee) return;
  int b = (i >= Ee) ? 1 : 0;
  int node = b * Nn + recv[i];
  int pos = atomicAdd(&cnt[node], 1);
  if (pos < CAP) {
    ids[(long)node * CAP + pos] = i;  // GLOBAL edge index
  } else {
    int s = atomicAdd(&cnt[NCNT], 1);
    if (s < SPILL_MAX) spill[s] = i;
  }
}

// Gather-sum (round-8-proven, ~260us = 2.0 TB/s random-512B wall: ~1M
// single-touch DRAM row activations at ~tRC over ~256 pseudo-channels;
// caches can't help single-touch data). ONE HALF-WAVE PER NODE, ids read
// as int4 -> 4 independent 512B edge-row loads in flight. No LDS, low
// VGPR, high occupancy. Output agg in BF16 (halves MLP-side traffic).
__global__ __launch_bounds__(256, 8) void gather_kernel(
    const float4* __restrict__ edge4, const int* __restrict__ cnt,
    const int* __restrict__ ids, const int* __restrict__ spill,
    const int* __restrict__ recv, unsigned short* __restrict__ aggb) {
  int half = (blockIdx.x * 256 + threadIdx.x) >> 5;  // global half-wave = node id
  int hl = threadIdx.x & 31;
  if (half >= NCNT) return;
  const int g = half;
  int deg0 = cnt[g];
  int deg = min(deg0, CAP);
  const int4* p4 = reinterpret_cast<const int4*>(ids + (long)g * CAP);
  float4 acc = make_float4(0.f, 0.f, 0.f, 0.f);

  int nfull = deg >> 2;
  for (int i = 0; i < nfull; ++i) {
    int4 q = p4[i];
    float4 v0 = edge4[(long)q.x * 32 + hl];
    float4 v1 = edge4[(long)q.y * 32 + hl];
    float4 v2 = edge4[(long)q.z * 32 + hl];
    float4 v3 = edge4[(long)q.w * 32 + hl];
    acc.x += (v0.x + v1.x) + (v2.x + v3.x);
    acc.y += (v0.y + v1.y) + (v2.y + v3.y);
    acc.z += (v0.z + v1.z) + (v2.z + v3.z);
    acc.w += (v0.w + v1.w) + (v2.w + v3.w);
  }
  int rem = deg & 3;
  if (rem) {
    int4 q = p4[nfull];
    float4 v0 = edge4[(long)q.x * 32 + hl];
    acc.x += v0.x; acc.y += v0.y; acc.z += v0.z; acc.w += v0.w;
    if (rem > 1) {
      float4 v1 = edge4[(long)q.y * 32 + hl];
      acc.x += v1.x; acc.y += v1.y; acc.z += v1.z; acc.w += v1.w;
    }
    if (rem > 2) {
      float4 v2 = edge4[(long)q.z * 32 + hl];
      acc.x += v2.x; acc.y += v2.y; acc.z += v2.z; acc.w += v2.w;
    }
  }
  // rare overflow: this node's extra edges sit in the spill list
  if (deg0 > CAP) {
    int sn = min(cnt[NCNT], SPILL_MAX);
    for (int s = 0; s < sn; ++s) {
      int e = spill[s];
      int nb = (e >= Ee) ? 1 : 0;
      if (nb * Nn + recv[e] == g) {
        float4 v = edge4[(long)e * 32 + hl];
        acc.x += v.x; acc.y += v.y; acc.z += v.z; acc.w += v.w;
      }
    }
  }
  ushort4 o;
  o.x = f2bf(acc.x); o.y = f2bf(acc.y); o.z = f2bf(acc.z); o.w = f2bf(acc.w);
  reinterpret_cast<ushort4*>(aggb)[(long)g * 32 + hl] = o;
}

// MLP, occupancy-tuned (round-13 analysis: 64-row/32KB-LDS version ran ~6
// waves/CU and ~60us vs ~25us floor). 32-ROW TILE, 128-THREAD BLOCKS, 16KB
// LDS, 2 waves each owning 16 rows -> ~2x blocks/CU, staging latency hidden
// by TLP. Same per-wave MFMA code as the proven round-8 kernel.
__global__ __launch_bounds__(128, 4) void mlp_kernel(
    const unsigned short* __restrict__ aggb, const float* __restrict__ node,
    const unsigned short* __restrict__ w1f, const unsigned short* __restrict__ w2f,
    const float* __restrict__ b1, const float* __restrict__ b2,
    float* __restrict__ out) {
  __shared__ __align__(16) char lds[32 * 512];  // 32 rows x 256 cols bf16
  const int tid = threadIdx.x;
  const int lane = tid & 63;
  const int wv = tid >> 6;          // 0..1
  const int blk = blockIdx.x;
  const int b = blk / TILES32;
  const int tile = blk - b * TILES32;
  const int row0 = tile * 32;
  const int rows = min(32, Nn - row0);

  // ---- stage vtin: agg half is already bf16; node half converts ----
#pragma unroll
  for (int ii = 0; ii < 8; ++ii) {  // cols 0..127 from aggb
    int idx = ii * 128 + tid;
    int row = idx >> 5;
    int c4 = idx & 31;
    ushort4 p = make_ushort4(0, 0, 0, 0);
    if (row < rows)
      p = reinterpret_cast<const ushort4*>(aggb)[((long)b * Nn + row0 + row) * 32 + c4];
    int byte = row * 512 + ((c4 * 8) ^ ((row & 7) << 4));
    *reinterpret_cast<ushort4*>(&lds[byte]) = p;
  }
#pragma unroll
  for (int ii = 0; ii < 8; ++ii) {  // cols 128..255 from node_data
    int idx = ii * 128 + tid;
    int row = idx >> 5;
    int c4 = idx & 31;
    float4 v = make_float4(0.f, 0.f, 0.f, 0.f);
    if (row < rows)
      v = reinterpret_cast<const float4*>(node)[((long)b * Nn + row0 + row) * 32 + c4];
    ushort4 p;
    p.x = f2bf(v.x); p.y = f2bf(v.y); p.z = f2bf(v.z); p.w = f2bf(v.w);
    int byte = row * 512 + ((256 + c4 * 8) ^ ((row & 7) << 4));
    *reinterpret_cast<ushort4*>(&lds[byte]) = p;
  }
  __syncthreads();

  // ---- GEMM1: h = relu(vtin @ W1 + b1) ----
  f32x4 acc[16];
#pragma unroll
  for (int ct = 0; ct < 16; ++ct) acc[ct] = (f32x4){0.f, 0.f, 0.f, 0.f};
  const int arow = wv * 16 + (lane & 15);
  const int abase = arow * 512;
  const int aswz = (arow & 7) << 4;
  const int koff = (lane >> 4) * 16;
#pragma unroll
  for (int ks = 0; ks < 8; ++ks) {
    short8 a = *reinterpret_cast<const short8*>(&lds[abase + ((ks * 64 + koff) ^ aswz)]);
#pragma unroll
    for (int ct = 0; ct < 16; ++ct) {
      short8 bf = *reinterpret_cast<const short8*>(w1f + ((ct * 8 + ks) * 64 + lane) * 8);
      acc[ct] = __builtin_amdgcn_mfma_f32_16x16x32_bf16(a, bf, acc[ct], 0, 0, 0);
    }
  }
  __syncthreads();  // both waves done reading vtin before overwrite

  // ---- bias + relu, write h (bf16, swizzled) ----
  {
    const int colb = lane & 15;
    const int rb = wv * 16 + (lane >> 4) * 4;
#pragma unroll
    for (int ct = 0; ct < 16; ++ct) {
      float bias = b1[ct * 16 + colb];
#pragma unroll
      for (int j = 0; j < 4; ++j) {
        float hv = acc[ct][j] + bias;
        hv = hv > 0.f ? hv : 0.f;
        int row = rb + j;
        int byte = row * 512 + (((ct * 16 + colb) * 2) ^ ((row & 7) << 4));
        *reinterpret_cast<unsigned short*>(&lds[byte]) = f2bf(hv);
      }
    }
  }
  __syncthreads();

  // ---- GEMM2: out = h @ W2 + b2 ----
  f32x4 acc2[8];
#pragma unroll
  for (int ct = 0; ct < 8; ++ct) acc2[ct] = (f32x4){0.f, 0.f, 0.f, 0.f};
#pragma unroll
  for (int ks = 0; ks < 8; ++ks) {
    short8 a = *reinterpret_cast<const short8*>(&lds[abase + ((ks * 64 + koff) ^ aswz)]);
#pragma unroll
    for (int ct = 0; ct < 8; ++ct) {
      short8 bf = *reinterpret_cast<const short8*>(w2f + ((ct * 8 + ks) * 64 + lane) * 8);
      acc2[ct] = __builtin_amdgcn_mfma_f32_16x16x32_bf16(a, bf, acc2[ct], 0, 0, 0);
    }
  }
  {
    const int colb = lane & 15;
    const int rb = wv * 16 + (lane >> 4) * 4;
#pragma unroll
    for (int ct = 0; ct < 8; ++ct) {
      float bias = b2[ct * 16 + colb];
#pragma unroll
      for (int j = 0; j < 4; ++j) {
        int r = rb + j;
        if (r < rows)
          out[((long)b * Nn + row0 + r) * DO + ct * 16 + colb] = acc2[ct][j] + bias;
      }
    }
  }
}

extern "C" void kernel_launch(void* const* d_in, const int* in_sizes, int n_in,
                              void* d_out, int out_size, void* d_ws, size_t ws_size,
                              hipStream_t stream) {
  const float* edge = (const float*)d_in[0];
  const float* node = (const float*)d_in[1];
  const float* W1   = (const float*)d_in[2];
  const float* b1   = (const float*)d_in[3];
  const float* W2   = (const float*)d_in[4];
  const float* b2   = (const float*)d_in[5];
  const int*   recv = (const int*)d_in[6];
  float* out = (float*)d_out;

  char* ws = (char*)d_ws;
  size_t off = 0;
  unsigned short* w1f = (unsigned short*)(ws + off); off += 131072;
  unsigned short* w2f = (unsigned short*)(ws + off); off += 65536;
  int* cnt   = (int*)(ws + off); off += 400016;                 // (NCNT+1)*4 padded
  int* spill = (int*)(ws + off); off += SPILL_MAX * 4;          // 262,144
  int* ids   = (int*)(ws + off); off += (size_t)NCNT * CAP * 4; // 19,200,000
  unsigned short* aggb = (unsigned short*)(ws + off);           // NCNT*128*2 = 25,600,000

  init_kernel<<<(NCNT + 256) / 256, 256, 0, stream>>>(W1, W2, w1f, w2f, cnt);
  fill_kernel<<<Bb * Ee / 256, 256, 0, stream>>>(recv, cnt, ids, spill);
  gather_kernel<<<NCNT / 8, 256, 0, stream>>>((const float4*)edge, cnt, ids, spill, recv, aggb);
  mlp_kernel<<<Bb * TILES32, 128, 0, stream>>>(aggb, node, w1f, w2f, b1, b2, out);
}